// Round 1
// baseline (483.574 us; speedup 1.0000x reference)
//
#include <hip/hip_runtime.h>
#include <hip/hip_bf16.h>

#define BB 16
#define SS 8192
#define HH 512
#define PP 32
#define NC 32   // s-chunks
#define CH 256  // rows per chunk = SS/NC

typedef __attribute__((ext_vector_type(8))) short short8;
typedef __attribute__((ext_vector_type(4))) float f32x4;

// ---- bf16 split helpers ----------------------------------------------------
__device__ inline unsigned short bf16_hi_trunc(float x) {
  union { float f; unsigned u; } v; v.f = x;
  return (unsigned short)(v.u >> 16);
}
__device__ inline unsigned short bf16_rne(float x) {
  union { float f; unsigned u; } v; v.f = x;
  unsigned r = v.u + 0x7FFFu + ((v.u >> 16) & 1u);
  return (unsigned short)(r >> 16);
}
__device__ inline float from_hi(unsigned short h) {
  union { unsigned u; float f; } v; v.u = ((unsigned)h) << 16;
  return v.f;
}
__device__ inline f32x4 max4(f32x4 a, f32x4 b) {
  f32x4 r; r.x = fmaxf(a.x, b.x); r.y = fmaxf(a.y, b.y);
  r.z = fmaxf(a.z, b.z); r.w = fmaxf(a.w, b.w); return r;
}
__device__ inline f32x4 exp4(f32x4 a) {
  f32x4 r; r.x = __expf(a.x); r.y = __expf(a.y);
  r.z = __expf(a.z); r.w = __expf(a.w); return r;
}
__device__ inline f32x4 fma_b(float a, f32x4 b, f32x4 c) {
  c.x = fmaf(a, b.x, c.x); c.y = fmaf(a, b.y, c.y);
  c.z = fmaf(a, b.z, c.z); c.w = fmaf(a, b.w, c.w); return c;
}
__device__ inline void cvt8(const float* xv, short8& bh, short8& bl) {
#pragma unroll
  for (int j = 0; j < 8; ++j) {
    unsigned short h = bf16_hi_trunc(xv[j]);
    bh[j] = (short)h;
    bl[j] = (short)bf16_rne(xv[j] - from_hi(h));
  }
}

// ---------------------------------------------------------------------------
// K0: pack probes [32][512] f32 into B-fragment layout (hi & lo bf16).
// Slot q = (nt*16 + kcg)*64 + lane holds 8 bf16: probes[nt*16 + (lane&15)]
//                                               [kcg*32 + (lane>>4)*8 + j]
// ---------------------------------------------------------------------------
__global__ void k_prep(const float* __restrict__ probes,
                       short* __restrict__ Ph, short* __restrict__ Pl) {
  int t = threadIdx.x;
  for (int q = t; q < 2048; q += 256) {
    int lane = q & 63, kcg = (q >> 6) & 15, nt = q >> 10;
    int p = nt * 16 + (lane & 15);
    int h0 = kcg * 32 + (lane >> 4) * 8;
#pragma unroll
    for (int j = 0; j < 8; ++j) {
      float f = probes[p * HH + h0 + j];
      unsigned short h = bf16_hi_trunc(f);
      Ph[q * 8 + j] = (short)h;
      Pl[q * 8 + j] = (short)bf16_rne(f - from_hi(h));
    }
  }
}

// ---------------------------------------------------------------------------
// K1 (fused): per (chunk, b): scores (MFMA, split bf16) -> LDS; chunk-local
// softmax stats (m_c, l_c); weights = exp(s - m_c) in LDS; ctx partial
// accumulated in registers reading x a second time while it is L2/L3-hot.
// Block = 512 threads = 8 waves. Wave w: 16-row m-tile in phase A,
// p-range [4w, 4w+4) in phase C. LDS ~53 KB -> 2 blocks/CU.
// ---------------------------------------------------------------------------
__global__ __launch_bounds__(512, 4) void k_fused(
    const float* __restrict__ x, const short* __restrict__ Ph,
    const short* __restrict__ Pl, float* __restrict__ pm,
    float* __restrict__ pl_, float* __restrict__ part) {
  __shared__ float sc_[CH][36];   // scores -> weights, padded stride (36 KB)
  __shared__ f32x4 sm[64][8];     // per-group max partials (8 KB)
  __shared__ f32x4 sl[64][8];     // per-group sumexp partials (8 KB)
  __shared__ f32x4 mS4[8];        // chunk max per p

  const int t = threadIdx.x;
  const int lane = t & 63, w = t >> 6;  // w in 0..7
  const int scnk = blockIdx.x;
  const int b = blockIdx.y;
  const size_t xbase = ((size_t)b * SS + (size_t)scnk * CH) * HH;

  // ---- phase A: scores for CH rows x 32 probes ----------------------------
#pragma unroll
  for (int tile = 0; tile < CH / 128; ++tile) {
    f32x4 acc0 = (f32x4){0.f, 0.f, 0.f, 0.f};
    f32x4 acc1 = (f32x4){0.f, 0.f, 0.f, 0.f};
    const int rl = tile * 128 + w * 16 + (lane & 15);
    const float* xr = x + xbase + (size_t)rl * HH + (lane >> 4) * 8;
#pragma unroll 2
    for (int kcg = 0; kcg < 16; ++kcg) {
      f32x4 xa = *(const f32x4*)(xr + kcg * 32);
      f32x4 xc = *(const f32x4*)(xr + kcg * 32 + 4);
      float xv[8] = {xa.x, xa.y, xa.z, xa.w, xc.x, xc.y, xc.z, xc.w};
      short8 xh, xl;
      cvt8(xv, xh, xl);
      short8 ph0 = *(const short8*)(Ph + ((size_t)(kcg * 64 + lane)) * 8);
      short8 pl0 = *(const short8*)(Pl + ((size_t)(kcg * 64 + lane)) * 8);
      short8 ph1 = *(const short8*)(Ph + ((size_t)((16 + kcg) * 64 + lane)) * 8);
      short8 pl1 = *(const short8*)(Pl + ((size_t)((16 + kcg) * 64 + lane)) * 8);
      acc0 = __builtin_amdgcn_mfma_f32_16x16x32_bf16(xh, ph0, acc0, 0, 0, 0);
      acc0 = __builtin_amdgcn_mfma_f32_16x16x32_bf16(xh, pl0, acc0, 0, 0, 0);
      acc0 = __builtin_amdgcn_mfma_f32_16x16x32_bf16(xl, ph0, acc0, 0, 0, 0);
      acc1 = __builtin_amdgcn_mfma_f32_16x16x32_bf16(xh, ph1, acc1, 0, 0, 0);
      acc1 = __builtin_amdgcn_mfma_f32_16x16x32_bf16(xh, pl1, acc1, 0, 0, 0);
      acc1 = __builtin_amdgcn_mfma_f32_16x16x32_bf16(xl, ph1, acc1, 0, 0, 0);
    }
    // C/D: col(lane&15) = p, row = (lane>>4)*4 + r
#pragma unroll
    for (int r = 0; r < 4; ++r) {
      int s_ = tile * 128 + w * 16 + (lane >> 4) * 4 + r;
      sc_[s_][lane & 15] = acc0[r];
      sc_[s_][16 + (lane & 15)] = acc1[r];
    }
  }
  __syncthreads();

  // ---- phase B: chunk-local (max, sumexp) per p over CH rows --------------
  {
    const int p4 = t & 7, sg = t >> 3;  // sg 0..63
    f32x4 m4 = (f32x4){-1e30f, -1e30f, -1e30f, -1e30f};
    f32x4 l4 = (f32x4){0.f, 0.f, 0.f, 0.f};
#pragma unroll
    for (int i = 0; i < CH / 64; ++i) {
      int s_ = sg + 64 * i;
      f32x4 v = *(const f32x4*)&sc_[s_][p4 * 4];
      f32x4 nm = max4(m4, v);
      l4 = l4 * exp4(m4 - nm) + exp4(v - nm);
      m4 = nm;
    }
    sm[sg][p4] = m4;
    sl[sg][p4] = l4;
  }
  __syncthreads();
  if (t < 8) {
    f32x4 M = sm[0][t], L = sl[0][t];
#pragma unroll
    for (int i = 1; i < 64; ++i) {
      f32x4 m2 = sm[i][t], l2 = sl[i][t];
      f32x4 nm = max4(M, m2);
      L = L * exp4(M - nm) + l2 * exp4(m2 - nm);
      M = nm;
    }
    mS4[t] = M;
    *(f32x4*)&pm[(size_t)(b * NC + scnk) * PP + t * 4] = M;
    *(f32x4*)&pl_[(size_t)(b * NC + scnk) * PP + t * 4] = L;
  }
  __syncthreads();

  // ---- phase B2: weights in place: w = exp(score - m_c[p]) ----------------
  {
    const float* mSf = (const float*)mS4;
#pragma unroll
    for (int i = 0; i < CH * PP / 512; ++i) {
      int idx = t + 512 * i;
      int s_ = idx >> 5, p = idx & 31;
      sc_[s_][p] = __expf(sc_[s_][p] - mSf[p]);
    }
  }
  __syncthreads();

  // ---- phase C: ctx partial; lane owns 8 h, wave owns p in [4w, 4w+4) -----
  const float* xrow = x + xbase + lane * 8;
  f32x4 acc[4][2];
#pragma unroll
  for (int pi = 0; pi < 4; ++pi) {
    acc[pi][0] = (f32x4){0.f, 0.f, 0.f, 0.f};
    acc[pi][1] = (f32x4){0.f, 0.f, 0.f, 0.f};
  }
  for (int jo = 0; jo < CH; jo += 4) {
    f32x4 xv0[4], xv1[4];
#pragma unroll
    for (int u = 0; u < 4; ++u) {
      const float* xp = xrow + (size_t)(jo + u) * HH;
      xv0[u] = *(const f32x4*)xp;
      xv1[u] = *(const f32x4*)(xp + 4);
    }
#pragma unroll
    for (int u = 0; u < 4; ++u) {
      f32x4 w0 = *(const f32x4*)&sc_[jo + u][w * 4];  // broadcast
      acc[0][0] = fma_b(w0.x, xv0[u], acc[0][0]);
      acc[0][1] = fma_b(w0.x, xv1[u], acc[0][1]);
      acc[1][0] = fma_b(w0.y, xv0[u], acc[1][0]);
      acc[1][1] = fma_b(w0.y, xv1[u], acc[1][1]);
      acc[2][0] = fma_b(w0.z, xv0[u], acc[2][0]);
      acc[2][1] = fma_b(w0.z, xv1[u], acc[2][1]);
      acc[3][0] = fma_b(w0.w, xv0[u], acc[3][0]);
      acc[3][1] = fma_b(w0.w, xv1[u], acc[3][1]);
    }
  }
#pragma unroll
  for (int pi = 0; pi < 4; ++pi) {
    int p = w * 4 + pi;
    float* o = part + (((size_t)scnk * BB + b) * PP + p) * HH + lane * 8;
    *(f32x4*)o = acc[pi][0];
    *(f32x4*)(o + 4) = acc[pi][1];
  }
}

// ---------------------------------------------------------------------------
// K2: merge NC chunk partials per (b,p): global (M,L) from (m_c,l_c), then
// out = sum_c part_c * exp(m_c - M) / L. Block = one (b,p), thread = 2 h.
// ---------------------------------------------------------------------------
__global__ __launch_bounds__(256) void k_merge(
    const float* __restrict__ part, const float* __restrict__ pm,
    const float* __restrict__ pl_, float* __restrict__ out) {
  const int bp = blockIdx.x;  // b*PP + p
  const int b = bp >> 5, p = bp & 31;
  const int t = threadIdx.x;

  float M = -1e30f;
#pragma unroll
  for (int c = 0; c < NC; ++c)
    M = fmaxf(M, pm[(size_t)(b * NC + c) * PP + p]);
  float f[NC];
  float L = 0.f;
#pragma unroll
  for (int c = 0; c < NC; ++c) {
    float e = __expf(pm[(size_t)(b * NC + c) * PP + p] - M);
    f[c] = e;
    L += pl_[(size_t)(b * NC + c) * PP + p] * e;
  }
  const float inv = 1.f / L;

  float sx = 0.f, sy = 0.f;
#pragma unroll
  for (int c = 0; c < NC; ++c) {
    const float* q = part + (((size_t)c * BB + b) * PP + p) * HH + t * 2;
    sx = fmaf(q[0], f[c], sx);
    sy = fmaf(q[1], f[c], sy);
  }
  float* o = out + (size_t)bp * HH + t * 2;
  o[0] = sx * inv;
  o[1] = sy * inv;
}

extern "C" void kernel_launch(void* const* d_in, const int* in_sizes, int n_in,
                              void* d_out, int out_size, void* d_ws, size_t ws_size,
                              hipStream_t stream) {
  const float* x = (const float*)d_in[0];       // [B,S,H] f32
  const float* probes = (const float*)d_in[1];  // [P,H]  f32
  float* out = (float*)d_out;                   // [B,P*H] f32

  float* part = (float*)d_ws;                   // NC*B*P*H = 33.6 MB
  float* pm = part + (size_t)NC * BB * PP * HH; // B*NC*P = 16384
  float* pl_ = pm + BB * NC * PP;               // 16384
  short* Ph = (short*)(pl_ + BB * NC * PP);     // 32 KB
  short* Pl = Ph + PP * HH;                     // 32 KB

  k_prep<<<1, 256, 0, stream>>>(probes, Ph, Pl);
  k_fused<<<dim3(NC, BB), 512, 0, stream>>>(x, Ph, Pl, pm, pl_, part);
  k_merge<<<dim3(BB * PP), 256, 0, stream>>>(part, pm, pl_, out);
}

// Round 2
// 463.181 us; speedup vs baseline: 1.0440x; 1.0440x over previous
//
#include <hip/hip_runtime.h>
#include <hip/hip_bf16.h>

#define BB 16
#define SS 8192
#define HH 512
#define PP 32
#define NC 32   // s-chunks
#define CH 256  // rows per chunk = SS/NC

typedef __attribute__((ext_vector_type(8))) short short8;
typedef __attribute__((ext_vector_type(4))) float f32x4;

// ---- bf16 split helpers ----------------------------------------------------
__device__ inline unsigned short bf16_hi_trunc(float x) {
  union { float f; unsigned u; } v; v.f = x;
  return (unsigned short)(v.u >> 16);
}
__device__ inline unsigned short bf16_rne(float x) {
  union { float f; unsigned u; } v; v.f = x;
  unsigned r = v.u + 0x7FFFu + ((v.u >> 16) & 1u);
  return (unsigned short)(r >> 16);
}
__device__ inline float from_hi(unsigned short h) {
  union { unsigned u; float f; } v; v.u = ((unsigned)h) << 16;
  return v.f;
}
__device__ inline f32x4 max4(f32x4 a, f32x4 b) {
  f32x4 r; r.x = fmaxf(a.x, b.x); r.y = fmaxf(a.y, b.y);
  r.z = fmaxf(a.z, b.z); r.w = fmaxf(a.w, b.w); return r;
}
__device__ inline f32x4 exp4(f32x4 a) {
  f32x4 r; r.x = __expf(a.x); r.y = __expf(a.y);
  r.z = __expf(a.z); r.w = __expf(a.w); return r;
}
__device__ inline f32x4 fma_b(float a, f32x4 b, f32x4 c) {
  c.x = fmaf(a, b.x, c.x); c.y = fmaf(a, b.y, c.y);
  c.z = fmaf(a, b.z, c.z); c.w = fmaf(a, b.w, c.w); return c;
}
__device__ inline void cvt8(const float* xv, short8& bh, short8& bl) {
#pragma unroll
  for (int j = 0; j < 8; ++j) {
    unsigned short h = bf16_hi_trunc(xv[j]);
    bh[j] = (short)h;
    bl[j] = (short)bf16_rne(xv[j] - from_hi(h));
  }
}
// async 16B global -> LDS (dest = wave-uniform base + lane*16)
__device__ inline void gll16(const float* g, float* l) {
  __builtin_amdgcn_global_load_lds(
      (const __attribute__((address_space(1))) unsigned int*)g,
      (__attribute__((address_space(3))) unsigned int*)l, 16, 0, 0);
}

// ---------------------------------------------------------------------------
// K0: pack probes [32][512] f32 into B-fragment layout (hi & lo bf16).
// ---------------------------------------------------------------------------
__global__ void k_prep(const float* __restrict__ probes,
                       short* __restrict__ Ph, short* __restrict__ Pl) {
  int t = threadIdx.x;
  for (int q = t; q < 2048; q += 256) {
    int lane = q & 63, kcg = (q >> 6) & 15, nt = q >> 10;
    int p = nt * 16 + (lane & 15);
    int h0 = kcg * 32 + (lane >> 4) * 8;
#pragma unroll
    for (int j = 0; j < 8; ++j) {
      float f = probes[p * HH + h0 + j];
      unsigned short h = bf16_hi_trunc(f);
      Ph[q * 8 + j] = (short)h;
      Pl[q * 8 + j] = (short)bf16_rne(f - from_hi(h));
    }
  }
}

// ---------------------------------------------------------------------------
// K1 (fused): per (chunk, b):
//  A: scores (split-bf16 MFMA, x from global) -> LDS
//  B: chunk-local (m,l); B2: weights = exp(s - m) in LDS
//  C: ctx partial; x sub-tiles (8 rows, 16 KB) staged global->LDS via
//     double-buffered global_load_lds with counted vmcnt(2) + raw s_barrier;
//     FMA loop reads x from LDS only (latency-proof).
// LDS: sc_ 36 KB + pool 32 KB (phase-B sm/sl/mS overlaid with phase-C
// staging buffers) = 68 KB -> 2 blocks/CU, 16 waves/CU.
// ---------------------------------------------------------------------------
__global__ __launch_bounds__(512, 4) void k_fused(
    const float* __restrict__ x, const short* __restrict__ Ph,
    const short* __restrict__ Pl, float* __restrict__ pm,
    float* __restrict__ pl_, float* __restrict__ part) {
  __shared__ float sc_[CH][36];   // scores -> weights, padded stride (36 KB)
  __shared__ f32x4 pool4[2048];   // 32 KB, phase-dependent use

  const int t = threadIdx.x;
  const int lane = t & 63, w = t >> 6;  // w in 0..7
  const int scnk = blockIdx.x;
  const int b = blockIdx.y;
  const size_t xbase = ((size_t)b * SS + (size_t)scnk * CH) * HH;

  // ---- phase A: scores for CH rows x 32 probes ----------------------------
#pragma unroll
  for (int tile = 0; tile < CH / 128; ++tile) {
    f32x4 acc0 = (f32x4){0.f, 0.f, 0.f, 0.f};
    f32x4 acc1 = (f32x4){0.f, 0.f, 0.f, 0.f};
    const int rl = tile * 128 + w * 16 + (lane & 15);
    const float* xr = x + xbase + (size_t)rl * HH + (lane >> 4) * 8;
#pragma unroll 4
    for (int kcg = 0; kcg < 16; ++kcg) {
      f32x4 xa = *(const f32x4*)(xr + kcg * 32);
      f32x4 xc = *(const f32x4*)(xr + kcg * 32 + 4);
      float xv[8] = {xa.x, xa.y, xa.z, xa.w, xc.x, xc.y, xc.z, xc.w};
      short8 xh, xl;
      cvt8(xv, xh, xl);
      short8 ph0 = *(const short8*)(Ph + ((size_t)(kcg * 64 + lane)) * 8);
      short8 pl0 = *(const short8*)(Pl + ((size_t)(kcg * 64 + lane)) * 8);
      short8 ph1 = *(const short8*)(Ph + ((size_t)((16 + kcg) * 64 + lane)) * 8);
      short8 pl1 = *(const short8*)(Pl + ((size_t)((16 + kcg) * 64 + lane)) * 8);
      acc0 = __builtin_amdgcn_mfma_f32_16x16x32_bf16(xh, ph0, acc0, 0, 0, 0);
      acc0 = __builtin_amdgcn_mfma_f32_16x16x32_bf16(xh, pl0, acc0, 0, 0, 0);
      acc0 = __builtin_amdgcn_mfma_f32_16x16x32_bf16(xl, ph0, acc0, 0, 0, 0);
      acc1 = __builtin_amdgcn_mfma_f32_16x16x32_bf16(xh, ph1, acc1, 0, 0, 0);
      acc1 = __builtin_amdgcn_mfma_f32_16x16x32_bf16(xh, pl1, acc1, 0, 0, 0);
      acc1 = __builtin_amdgcn_mfma_f32_16x16x32_bf16(xl, ph1, acc1, 0, 0, 0);
    }
#pragma unroll
    for (int r = 0; r < 4; ++r) {
      int s_ = tile * 128 + w * 16 + (lane >> 4) * 4 + r;
      sc_[s_][lane & 15] = acc0[r];
      sc_[s_][16 + (lane & 15)] = acc1[r];
    }
  }
  __syncthreads();

  // ---- phase B: chunk-local (max, sumexp) per p over CH rows --------------
  f32x4 (*sm)[8] = reinterpret_cast<f32x4(*)[8]>(pool4);         // 8 KB
  f32x4 (*sl)[8] = reinterpret_cast<f32x4(*)[8]>(pool4 + 512);   // 8 KB
  f32x4* mS4 = pool4 + 1024;                                      // 128 B
  {
    const int p4 = t & 7, sg = t >> 3;  // sg 0..63
    f32x4 m4 = (f32x4){-1e30f, -1e30f, -1e30f, -1e30f};
    f32x4 l4 = (f32x4){0.f, 0.f, 0.f, 0.f};
#pragma unroll
    for (int i = 0; i < CH / 64; ++i) {
      int s_ = sg + 64 * i;
      f32x4 v = *(const f32x4*)&sc_[s_][p4 * 4];
      f32x4 nm = max4(m4, v);
      l4 = l4 * exp4(m4 - nm) + exp4(v - nm);
      m4 = nm;
    }
    sm[sg][p4] = m4;
    sl[sg][p4] = l4;
  }
  __syncthreads();
  if (t < 8) {
    f32x4 M = sm[0][t], L = sl[0][t];
#pragma unroll
    for (int i = 1; i < 64; ++i) {
      f32x4 m2 = sm[i][t], l2 = sl[i][t];
      f32x4 nm = max4(M, m2);
      L = L * exp4(M - nm) + l2 * exp4(m2 - nm);
      M = nm;
    }
    mS4[t] = M;
    *(f32x4*)&pm[(size_t)(b * NC + scnk) * PP + t * 4] = M;
    *(f32x4*)&pl_[(size_t)(b * NC + scnk) * PP + t * 4] = L;
  }
  __syncthreads();

  // ---- phase B2: weights in place: w = exp(score - m_c[p]) ----------------
  {
    const float* mSf = (const float*)mS4;
#pragma unroll
    for (int i = 0; i < CH * PP / 512; ++i) {
      int idx = t + 512 * i;
      int s_ = idx >> 5, p = idx & 31;
      sc_[s_][p] = __expf(sc_[s_][p] - mSf[p]);
    }
  }
  __syncthreads();  // after this, pool4 is repurposed as x staging

  // ---- phase C: ctx partial from LDS-staged x -----------------------------
  // 32 sub-tiles of 8 rows (16 KB each), double-buffered. Wave w stages
  // floats [w*512, w*512+512) of each tile via 2x global_load_lds(16B).
  float* xs = (float*)pool4;            // [2][4096] floats
  const float* xg = x + xbase;
  const int so = w * 512 + lane * 4;    // per-lane global float offset
  const int do_ = w * 512;              // wave-uniform LDS float offset

  f32x4 acc[4][2];
#pragma unroll
  for (int pi = 0; pi < 4; ++pi) {
    acc[pi][0] = (f32x4){0.f, 0.f, 0.f, 0.f};
    acc[pi][1] = (f32x4){0.f, 0.f, 0.f, 0.f};
  }

  // prologue: stage tile 0 -> buf 0
  gll16(xg + so, xs + do_);
  gll16(xg + so + 256, xs + do_ + 256);

  for (int st = 0; st < 32; ++st) {
    const int nst = (st + 1) & 31;      // st=31 re-stages tile 0 (harmless dummy)
    const int nbuf = (st + 1) & 1;
    gll16(xg + (size_t)nst * 4096 + so, xs + nbuf * 4096 + do_);
    gll16(xg + (size_t)nst * 4096 + so + 256, xs + nbuf * 4096 + do_ + 256);
    asm volatile("s_waitcnt vmcnt(2)" ::: "memory");  // cur tile landed; next 2 in flight
    __builtin_amdgcn_s_barrier();
    __builtin_amdgcn_sched_barrier(0);
    const float* xb = xs + (st & 1) * 4096;
#pragma unroll
    for (int j = 0; j < 8; ++j) {
      f32x4 xv0 = *(const f32x4*)(xb + j * 512 + lane * 8);
      f32x4 xv1 = *(const f32x4*)(xb + j * 512 + lane * 8 + 4);
      f32x4 w0 = *(const f32x4*)&sc_[st * 8 + j][w * 4];  // broadcast
      acc[0][0] = fma_b(w0.x, xv0, acc[0][0]);
      acc[0][1] = fma_b(w0.x, xv1, acc[0][1]);
      acc[1][0] = fma_b(w0.y, xv0, acc[1][0]);
      acc[1][1] = fma_b(w0.y, xv1, acc[1][1]);
      acc[2][0] = fma_b(w0.z, xv0, acc[2][0]);
      acc[2][1] = fma_b(w0.z, xv1, acc[2][1]);
      acc[3][0] = fma_b(w0.w, xv0, acc[3][0]);
      acc[3][1] = fma_b(w0.w, xv1, acc[3][1]);
    }
    __builtin_amdgcn_sched_barrier(0);
    __builtin_amdgcn_s_barrier();
  }

#pragma unroll
  for (int pi = 0; pi < 4; ++pi) {
    int p = w * 4 + pi;
    float* o = part + (((size_t)scnk * BB + b) * PP + p) * HH + lane * 8;
    *(f32x4*)o = acc[pi][0];
    *(f32x4*)(o + 4) = acc[pi][1];
  }
}

// ---------------------------------------------------------------------------
// K2: merge NC chunk partials per (b,p).
// ---------------------------------------------------------------------------
__global__ __launch_bounds__(256) void k_merge(
    const float* __restrict__ part, const float* __restrict__ pm,
    const float* __restrict__ pl_, float* __restrict__ out) {
  const int bp = blockIdx.x;  // b*PP + p
  const int b = bp >> 5, p = bp & 31;
  const int t = threadIdx.x;

  float M = -1e30f;
#pragma unroll
  for (int c = 0; c < NC; ++c)
    M = fmaxf(M, pm[(size_t)(b * NC + c) * PP + p]);
  float f[NC];
  float L = 0.f;
#pragma unroll
  for (int c = 0; c < NC; ++c) {
    float e = __expf(pm[(size_t)(b * NC + c) * PP + p] - M);
    f[c] = e;
    L += pl_[(size_t)(b * NC + c) * PP + p] * e;
  }
  const float inv = 1.f / L;

  float sx = 0.f, sy = 0.f;
#pragma unroll
  for (int c = 0; c < NC; ++c) {
    const float* q = part + (((size_t)c * BB + b) * PP + p) * HH + t * 2;
    sx = fmaf(q[0], f[c], sx);
    sy = fmaf(q[1], f[c], sy);
  }
  float* o = out + (size_t)bp * HH + t * 2;
  o[0] = sx * inv;
  o[1] = sy * inv;
}

extern "C" void kernel_launch(void* const* d_in, const int* in_sizes, int n_in,
                              void* d_out, int out_size, void* d_ws, size_t ws_size,
                              hipStream_t stream) {
  const float* x = (const float*)d_in[0];       // [B,S,H] f32
  const float* probes = (const float*)d_in[1];  // [P,H]  f32
  float* out = (float*)d_out;                   // [B,P*H] f32

  float* part = (float*)d_ws;                   // NC*B*P*H = 33.6 MB
  float* pm = part + (size_t)NC * BB * PP * HH; // B*NC*P = 16384
  float* pl_ = pm + BB * NC * PP;               // 16384
  short* Ph = (short*)(pl_ + BB * NC * PP);     // 32 KB
  short* Pl = Ph + PP * HH;                     // 32 KB

  k_prep<<<1, 256, 0, stream>>>(probes, Ph, Pl);
  k_fused<<<dim3(NC, BB), 512, 0, stream>>>(x, Ph, Pl, pm, pl_, part);
  k_merge<<<dim3(BB * PP), 256, 0, stream>>>(part, pm, pl_, out);
}